// Round 5
// baseline (821.235 us; speedup 1.0000x reference)
//
#include <hip/hip_runtime.h>

#define TT 1024   // timesteps
#define SS 16     // layer skew = barrier period K; buffer depth D = 2K = 32
// batch = 512 sequences, 1 per block; 3 waves/block = 1 per GRU layer.
// Weights in registers. h-vectors flow through a 32-slot LDS ring per layer;
// __syncthreads only every 16 steps (skew-16 pipeline makes this safe):
//   consumer at iter i reads producer's iter i-16  -> s >= K   (RAW ok)
//   slot overwritten every 32 iters, read <=31 iters after write -> D >= s+K (WAR ok)
// Within a wave, own-h write->read is same-wave program order (lgkmcnt), no barrier.

__device__ __forceinline__ float fast_sigmoid(float x) {
    float e = __builtin_amdgcn_exp2f(x * -1.4426950408889634f);
    return __builtin_amdgcn_rcpf(1.0f + e);
}
__device__ __forceinline__ float fast_tanh(float x) {
    float e = __builtin_amdgcn_exp2f(x * -2.8853900817779268f);
    return fmaf(2.0f, __builtin_amdgcn_rcpf(1.0f + e), -1.0f);
}

__device__ __forceinline__ void acc3(const float4 w0, const float4 w1, const float4 w2,
                                     const float4 v, float4& a0, float4& a1, float4& a2) {
    a0.x = fmaf(w0.x, v.x, a0.x); a0.y = fmaf(w0.y, v.y, a0.y);
    a0.z = fmaf(w0.z, v.z, a0.z); a0.w = fmaf(w0.w, v.w, a0.w);
    a1.x = fmaf(w1.x, v.x, a1.x); a1.y = fmaf(w1.y, v.y, a1.y);
    a1.z = fmaf(w1.z, v.z, a1.z); a1.w = fmaf(w1.w, v.w, a1.w);
    a2.x = fmaf(w2.x, v.x, a2.x); a2.y = fmaf(w2.y, v.y, a2.y);
    a2.z = fmaf(w2.z, v.z, a2.z); a2.w = fmaf(w2.w, v.w, a2.w);
}
__device__ __forceinline__ float hsum(const float4 a) {
    return (a.x + a.y) + (a.z + a.w);
}

// LDS: ybuf[layer][slot(32)][copy(2)*32]  (each copy is a full h vector; copy c
// is written by lanes kh==c, so every write is 64 distinct addresses, no branch)
__global__ __launch_bounds__(192) void gru3_fused(
    const float* __restrict__ x,
    const float* __restrict__ Wih1, const float* __restrict__ Whh1,
    const float* __restrict__ bih1, const float* __restrict__ bhh1,
    const float* __restrict__ Wih2, const float* __restrict__ Whh2,
    const float* __restrict__ bih2, const float* __restrict__ bhh2,
    const float* __restrict__ Wih3, const float* __restrict__ Whh3,
    const float* __restrict__ bih3, const float* __restrict__ bhh3,
    float* __restrict__ out)
{
    __shared__ float ybuf[3 * 32 * 64];   // 6144 floats = 24 KB
    __shared__ float xs[TT];              // 4 KB

    const int tid  = threadIdx.x;
    const int wid  = tid >> 6;        // wave = layer 0..2
    const int lane = tid & 63;
    const int h    = lane & 31;       // hidden unit
    const int kh   = lane >> 5;       // k-half (heavy waves); copy index (all waves)
    const int k0   = kh * 16;
    const int bb   = (int)blockIdx.x; // batch index 0..511

    // ---- one-time staging ----
    {
        float4 z4 = make_float4(0.f, 0.f, 0.f, 0.f);
        for (int j = tid; j < 1536; j += 192) ((float4*)ybuf)[j] = z4;  // zero ring
        const float4* xr4 = (const float4*)(x + bb * TT);
        for (int j = tid; j < TT / 4; j += 192) ((float4*)xs)[j] = xr4[j];
    }

    // ---- per-lane register weights (unified array so both paths share regs) ----
    // heavy (wid>=1): w[0..2] = Whh gate rows, k-slice k0..k0+15
    //                 w[3..5] = Wih gate rows, k-slice k0..k0+15
    // wave0:          w[0..2] = Whh1 gate rows, k 0..15
    //                 w[3..5] = Whh1 gate rows, k 16..31   (full-k, no reduce)
    float4 w[6][4];
    if (wid == 0) {
#pragma unroll
        for (int g = 0; g < 3; ++g)
#pragma unroll
            for (int j = 0; j < 4; ++j) {
                w[g][j]     = *(const float4*)(Whh1 + (g * 32 + h) * 32 + 4 * j);
                w[3 + g][j] = *(const float4*)(Whh1 + (g * 32 + h) * 32 + 16 + 4 * j);
            }
    } else {
        const float* Whh = (wid == 1) ? Whh2 : Whh3;
        const float* Wih = (wid == 1) ? Wih2 : Wih3;
#pragma unroll
        for (int g = 0; g < 3; ++g)
#pragma unroll
            for (int j = 0; j < 4; ++j) {
                w[g][j]     = *(const float4*)(Whh + (g * 32 + h) * 32 + k0 + 4 * j);
                w[3 + g][j] = *(const float4*)(Wih + (g * 32 + h) * 32 + k0 + 4 * j);
            }
    }

    const float* bihp = (wid == 0) ? bih1 : (wid == 1) ? bih2 : bih3;
    const float* bhhp = (wid == 0) ? bhh1 : (wid == 1) ? bhh2 : bhh3;
    const float brz_r = bihp[h]      + bhhp[h];
    const float brz_z = bihp[32 + h] + bhhp[32 + h];
    const float b_in  = bihp[64 + h];
    const float b_hn  = bhhp[64 + h];
    float wi_r = 0.f, wi_z = 0.f, wi_n = 0.f;
    if (wid == 0) { wi_r = Wih1[h]; wi_z = Wih1[32 + h]; wi_n = Wih1[64 + h]; }

    const int wlane    = kh * 32 + h;                       // write lane offset
    const int rlane    = (wid == 0) ? kh * 32 : kh * 32 + k0; // read lane offset
    const int own_off  = wid * 2048;                        // layer stride 32*64
    const int prev_off = (wid - 1) * 2048;

    __syncthreads();

    float hprev = 0.0f;
    // at iteration i, wave L computes timestep t = i - 16*L
    for (int i = 0; i < TT + 2 * SS; ++i) {
        const int t = i - (wid << 4);
        if (t >= 0 && t < TT) {
            const int slot  = t & 31;
            const int pslot = (t - 1) & 31;

            float xv = 0.f;
            if (wid == 0) xv = xs[t];   // early issue, hidden under dots

            // issue input-h reads first (no same-wave dep), then own-h reads
            // (dep on prev step's write); compute ih-dot while own-h in flight.
            const float* ownp = &ybuf[own_off + pslot * 64 + rlane];
            const float* inp  = (wid == 0) ? (ownp + 16)
                                           : &ybuf[prev_off + slot * 64 + rlane];
            float4 vIn[4], vOwn[4];
#pragma unroll
            for (int j = 0; j < 4; ++j) vIn[j]  = ((const float4*)inp)[j];
#pragma unroll
            for (int j = 0; j < 4; ++j) vOwn[j] = ((const float4*)ownp)[j];

            float4 b0 = make_float4(0.f, 0.f, 0.f, 0.f), b1 = b0, b2 = b0;
#pragma unroll
            for (int j = 0; j < 4; ++j) acc3(w[3][j], w[4][j], w[5][j], vIn[j], b0, b1, b2);
            float4 a0 = make_float4(0.f, 0.f, 0.f, 0.f), a1 = a0, a2 = a0;
#pragma unroll
            for (int j = 0; j < 4; ++j) acc3(w[0][j], w[1][j], w[2][j], vOwn[j], a0, a1, a2);

            const float sr = hsum(a0), sz = hsum(a1), sn = hsum(a2);
            const float tr = hsum(b0), tz = hsum(b1), tn = hsum(b2);

            float r, z, nn;
            if (wid == 0) {
                // full-k: sr+tr etc are complete hh dots; input term is x*wi
                r  = fast_sigmoid(fmaf(xv, wi_r, sr + tr + brz_r));
                z  = fast_sigmoid(fmaf(xv, wi_z, sz + tz + brz_z));
                nn = fast_tanh(fmaf(xv, wi_n, b_in) + r * (sn + tn + b_hn));
            } else {
                // k-split: combine ih+hh partials first, then one reduce each
                float cr = sr + tr;  cr += __shfl_xor(cr, 32);
                float cz = sz + tz;  cz += __shfl_xor(cz, 32);
                float ci = tn;       ci += __shfl_xor(ci, 32);   // i_n partial
                float ch = sn;       ch += __shfl_xor(ch, 32);   // h_n partial
                r  = fast_sigmoid(cr + brz_r);
                z  = fast_sigmoid(cz + brz_z);
                nn = fast_tanh(ci + b_in + r * (ch + b_hn));
            }
            const float hn = fmaf(z, hprev - nn, nn);
            hprev = hn;
            ybuf[own_off + slot * 64 + wlane] = hn;          // publish h(t), 64 distinct addrs
            if (wid == 2 && kh == 0)
                out[(unsigned)(t * 16384 + bb * 32 + h)] = hn;   // [T,B,H] flat
        }
        if ((i & 15) == 15) __syncthreads();   // barrier only every 16 steps
    }
}

extern "C" void kernel_launch(void* const* d_in, const int* in_sizes, int n_in,
                              void* d_out, int out_size, void* d_ws, size_t ws_size,
                              hipStream_t stream) {
    const float* x    = (const float*)d_in[0];
    const float* Wih1 = (const float*)d_in[1];
    const float* Whh1 = (const float*)d_in[2];
    const float* bih1 = (const float*)d_in[3];
    const float* bhh1 = (const float*)d_in[4];
    const float* Wih2 = (const float*)d_in[5];
    const float* Whh2 = (const float*)d_in[6];
    const float* bih2 = (const float*)d_in[7];
    const float* bhh2 = (const float*)d_in[8];
    const float* Wih3 = (const float*)d_in[9];
    const float* Whh3 = (const float*)d_in[10];
    const float* bih3 = (const float*)d_in[11];
    const float* bhh3 = (const float*)d_in[12];

    gru3_fused<<<dim3(512), dim3(192), 0, stream>>>(
        x, Wih1, Whh1, bih1, bhh1,
        Wih2, Whh2, bih2, bhh2,
        Wih3, Whh3, bih3, bhh3,
        (float*)d_out);
}

// Round 6
// 680.617 us; speedup vs baseline: 1.2066x; 1.2066x over previous
//
#include <hip/hip_runtime.h>

#define TT 1024   // timesteps
// batch = 512 sequences, 1 per block; 3 waves/block = 1 per GRU layer.
// Weights in registers (k-split across wave halves), packed v_pk_fma_f32 math.
// h flows through a tiny parity-double-buffered LDS vector, 1 barrier/step.
// __launch_bounds__(192,2): cap at 2 waves/SIMD -> up to 256 VGPR, so the
// 96 weight floats + working set actually STAY resident (R4/R5 showed
// VGPR_Count=80 => compiler was re-loading weights in-loop).

typedef float v2f __attribute__((ext_vector_type(2)));

__device__ __forceinline__ v2f pk_mul(v2f a, v2f b) {
    v2f d; asm("v_pk_mul_f32 %0, %1, %2" : "=v"(d) : "v"(a), "v"(b)); return d;
}
__device__ __forceinline__ v2f pk_fma(v2f a, v2f b, v2f c) {
    v2f d; asm("v_pk_fma_f32 %0, %1, %2, %3" : "=v"(d) : "v"(a), "v"(b), "v"(c)); return d;
}
__device__ __forceinline__ v2f pk_add(v2f a, v2f b) {
    v2f d; asm("v_pk_add_f32 %0, %1, %2" : "=v"(d) : "v"(a), "v"(b)); return d;
}

__device__ __forceinline__ float fast_sigmoid(float x) {
    float e = __builtin_amdgcn_exp2f(x * -1.4426950408889634f);
    return __builtin_amdgcn_rcpf(1.0f + e);
}
__device__ __forceinline__ float fast_tanh(float x) {
    float e = __builtin_amdgcn_exp2f(x * -2.8853900817779268f);
    return fmaf(2.0f, __builtin_amdgcn_rcpf(1.0f + e), -1.0f);
}

// 3 gate dot products over a 16-k slice held as 8 packed f32 pairs.
// 8 pk ops per gate (1 mul + 7 fma as two chains) + 1 pk_add + 1 scalar add.
__device__ __forceinline__ void dot3(const v2f (&w)[3][8], const v2f (&v)[8], float (&d)[3]) {
#pragma unroll
    for (int g = 0; g < 3; ++g) {
        v2f a = pk_mul(w[g][0], v[0]);
        v2f b = pk_mul(w[g][1], v[1]);
        a = pk_fma(w[g][2], v[2], a);
        b = pk_fma(w[g][3], v[3], b);
        a = pk_fma(w[g][4], v[4], a);
        b = pk_fma(w[g][5], v[5], b);
        a = pk_fma(w[g][6], v[6], a);
        b = pk_fma(w[g][7], v[7], b);
        a = pk_add(a, b);
        d[g] = a.x + a.y;
    }
}

// 16 consecutive floats -> 8 packed pairs (two b128 loads, subreg splits are free)
__device__ __forceinline__ void load8(const float* p, v2f (&v)[8]) {
    const float4 f0 = ((const float4*)p)[0];
    const float4 f1 = ((const float4*)p)[1];
    const float4 f2 = ((const float4*)p)[2];
    const float4 f3 = ((const float4*)p)[3];
    v[0] = v2f{f0.x, f0.y}; v[1] = v2f{f0.z, f0.w};
    v[2] = v2f{f1.x, f1.y}; v[3] = v2f{f1.z, f1.w};
    v[4] = v2f{f2.x, f2.y}; v[5] = v2f{f2.z, f2.w};
    v[6] = v2f{f3.x, f3.y}; v[7] = v2f{f3.z, f3.w};
}

__global__ __launch_bounds__(192, 2) void gru3_fused(
    const float* __restrict__ x,
    const float* __restrict__ Wih1, const float* __restrict__ Whh1,
    const float* __restrict__ bih1, const float* __restrict__ bhh1,
    const float* __restrict__ Wih2, const float* __restrict__ Whh2,
    const float* __restrict__ bih2, const float* __restrict__ bhh2,
    const float* __restrict__ Wih3, const float* __restrict__ Whh3,
    const float* __restrict__ bih3, const float* __restrict__ bhh3,
    float* __restrict__ out)
{
    __shared__ float ybuf[3 * 2 * 32];   // [layer][parity][h]
    __shared__ float xs[TT];             // staged x row

    const int tid  = threadIdx.x;
    const int wid  = __builtin_amdgcn_readfirstlane(tid >> 6);  // scalar layer id
    const int lane = tid & 63;
    const int h    = lane & 31;       // hidden unit
    const int kh   = lane >> 5;       // k-half
    const int k0   = kh * 16;
    const int bb   = (int)blockIdx.x; // batch index 0..511

    // ---- one-time staging ----
    if (tid < 192) ybuf[tid] = 0.0f;
    {
        const float4* xr4 = (const float4*)(x + bb * TT);
        for (int j = tid; j < TT / 4; j += 192) ((float4*)xs)[j] = xr4[j];
    }

    // ---- per-lane register weights (packed pairs), k-slice k0..k0+15 ----
    const float* WhhP = (wid == 0) ? Whh1 : (wid == 1) ? Whh2 : Whh3;
    const float* WihP = (wid == 0) ? Whh1 : (wid == 1) ? Wih2 : Wih3;  // dummy for wave0
    v2f whh[3][8], wih[3][8];
#pragma unroll
    for (int g = 0; g < 3; ++g) {
        load8(WhhP + (g * 32 + h) * 32 + k0, whh[g]);
        load8(WihP + (g * 32 + h) * 32 + k0, wih[g]);
    }

    const float* bihp = (wid == 0) ? bih1 : (wid == 1) ? bih2 : bih3;
    const float* bhhp = (wid == 0) ? bhh1 : (wid == 1) ? bhh2 : bhh3;
    const float brz_r = bihp[h]      + bhhp[h];
    const float brz_z = bihp[32 + h] + bhhp[32 + h];
    const float b_in  = bihp[64 + h];
    const float b_hn  = bhhp[64 + h];
    float wi_r = 0.f, wi_z = 0.f, wi_n = 0.f;
    if (wid == 0) { wi_r = Wih1[h]; wi_z = Wih1[32 + h]; wi_n = Wih1[64 + h]; }

    __syncthreads();

    float hprev = 0.0f;
    // pipelined: at iteration i, wave L computes timestep t = i - L
    for (int i = 0; i < TT + 2; ++i) {
        const int t = i - wid;           // scalar
        if (t >= 0 && t < TT) {          // scalar branch
            const int p = t & 1;

            v2f vi[8], vo[8];
            if (wid != 0) load8(ybuf + (wid - 1) * 64 + p * 32 + k0, vi);
            load8(ybuf + wid * 64 + (p ^ 1) * 32 + k0, vo);

            float di[3], dh[3];
            float xv = 0.f;
            if (wid == 0) xv = xs[t];
            if (wid != 0) dot3(wih, vi, di);   // runs while vo reads in flight
            dot3(whh, vo, dh);

            float r, z, nn;
            if (wid != 0) {
                float cr = dh[0] + di[0]; cr += __shfl_xor(cr, 32);
                float cz = dh[1] + di[1]; cz += __shfl_xor(cz, 32);
                float ci = di[2];         ci += __shfl_xor(ci, 32);
                float ch = dh[2];         ch += __shfl_xor(ch, 32);
                r  = fast_sigmoid(cr + brz_r);
                z  = fast_sigmoid(cz + brz_z);
                nn = fast_tanh(ci + b_in + r * (ch + b_hn));
            } else {
                float sr = dh[0]; sr += __shfl_xor(sr, 32);
                float sz = dh[1]; sz += __shfl_xor(sz, 32);
                float sn = dh[2]; sn += __shfl_xor(sn, 32);
                r  = fast_sigmoid(fmaf(xv, wi_r, sr + brz_r));
                z  = fast_sigmoid(fmaf(xv, wi_z, sz + brz_z));
                nn = fast_tanh(fmaf(xv, wi_n, b_in) + r * (sn + b_hn));
            }
            const float hn = fmaf(z, hprev - nn, nn);
            hprev = hn;

            if (kh == 0) {
                ybuf[wid * 64 + p * 32 + h] = hn;                 // publish h(t)
                if (wid == 2) out[t * 16384 + bb * 32 + h] = hn;  // [T,B,H] flat
            }
        }
        __syncthreads();
    }
}

extern "C" void kernel_launch(void* const* d_in, const int* in_sizes, int n_in,
                              void* d_out, int out_size, void* d_ws, size_t ws_size,
                              hipStream_t stream) {
    const float* x    = (const float*)d_in[0];
    const float* Wih1 = (const float*)d_in[1];
    const float* Whh1 = (const float*)d_in[2];
    const float* bih1 = (const float*)d_in[3];
    const float* bhh1 = (const float*)d_in[4];
    const float* Wih2 = (const float*)d_in[5];
    const float* Whh2 = (const float*)d_in[6];
    const float* bih2 = (const float*)d_in[7];
    const float* bhh2 = (const float*)d_in[8];
    const float* Wih3 = (const float*)d_in[9];
    const float* Whh3 = (const float*)d_in[10];
    const float* bih3 = (const float*)d_in[11];
    const float* bhh3 = (const float*)d_in[12];

    gru3_fused<<<dim3(512), dim3(192), 0, stream>>>(
        x, Wih1, Whh1, bih1, bhh1,
        Wih2, Whh2, bih2, bhh2,
        Wih3, Whh3, bih3, bhh3,
        (float*)d_out);
}

// Round 7
// 644.255 us; speedup vs baseline: 1.2747x; 1.0564x over previous
//
#include <hip/hip_runtime.h>

#define TT 1024   // timesteps
// batch = 512 sequences, 1 per block; 3 waves/block = 1 per GRU layer.
// Weights in registers (k-split across wave halves), packed v_pk_fma_f32 math.
// R6 lesson: VGPR_Count=76 proved the compiler was RE-LOADING the 96 weight
// floats from global every step. Fix: opaque asm pin ("+v") after the one-time
// load forces true register residency. Also: in-loop barrier is lgkm-only
// (no vmcnt drain), so wave2's per-step global store stays fire-and-forget.

typedef float v2f __attribute__((ext_vector_type(2)));

__device__ __forceinline__ v2f pk_mul(v2f a, v2f b) {
    v2f d; asm("v_pk_mul_f32 %0, %1, %2" : "=v"(d) : "v"(a), "v"(b)); return d;
}
__device__ __forceinline__ v2f pk_fma(v2f a, v2f b, v2f c) {
    v2f d; asm("v_pk_fma_f32 %0, %1, %2, %3" : "=v"(d) : "v"(a), "v"(b), "v"(c)); return d;
}
__device__ __forceinline__ v2f pk_add(v2f a, v2f b) {
    v2f d; asm("v_pk_add_f32 %0, %1, %2" : "=v"(d) : "v"(a), "v"(b)); return d;
}

__device__ __forceinline__ float fast_sigmoid(float x) {
    float e = __builtin_amdgcn_exp2f(x * -1.4426950408889634f);
    return __builtin_amdgcn_rcpf(1.0f + e);
}
__device__ __forceinline__ float fast_tanh(float x) {
    float e = __builtin_amdgcn_exp2f(x * -2.8853900817779268f);
    return fmaf(2.0f, __builtin_amdgcn_rcpf(1.0f + e), -1.0f);
}

// 3 gate dot products over a 16-k slice held as 8 packed f32 pairs.
__device__ __forceinline__ void dot3(const v2f (&w)[3][8], const v2f (&v)[8], float (&d)[3]) {
#pragma unroll
    for (int g = 0; g < 3; ++g) {
        v2f a = pk_mul(w[g][0], v[0]);
        v2f b = pk_mul(w[g][1], v[1]);
        a = pk_fma(w[g][2], v[2], a);
        b = pk_fma(w[g][3], v[3], b);
        a = pk_fma(w[g][4], v[4], a);
        b = pk_fma(w[g][5], v[5], b);
        a = pk_fma(w[g][6], v[6], a);
        b = pk_fma(w[g][7], v[7], b);
        a = pk_add(a, b);
        d[g] = a.x + a.y;
    }
}

// 16 consecutive floats -> 8 packed pairs
__device__ __forceinline__ void load8(const float* p, v2f (&v)[8]) {
    const float4 f0 = ((const float4*)p)[0];
    const float4 f1 = ((const float4*)p)[1];
    const float4 f2 = ((const float4*)p)[2];
    const float4 f3 = ((const float4*)p)[3];
    v[0] = v2f{f0.x, f0.y}; v[1] = v2f{f0.z, f0.w};
    v[2] = v2f{f1.x, f1.y}; v[3] = v2f{f1.z, f1.w};
    v[4] = v2f{f2.x, f2.y}; v[5] = v2f{f2.z, f2.w};
    v[6] = v2f{f3.x, f3.y}; v[7] = v2f{f3.z, f3.w};
}

// lgkm-only block barrier: LDS writes visible, global stores NOT drained.
__device__ __forceinline__ void sync_lgkm() {
    __builtin_amdgcn_sched_barrier(0);
    asm volatile("s_waitcnt lgkmcnt(0)" ::: "memory");
    __builtin_amdgcn_s_barrier();
    __builtin_amdgcn_sched_barrier(0);
}

__global__ __launch_bounds__(192, 2) void gru3_fused(
    const float* __restrict__ x,
    const float* __restrict__ Wih1, const float* __restrict__ Whh1,
    const float* __restrict__ bih1, const float* __restrict__ bhh1,
    const float* __restrict__ Wih2, const float* __restrict__ Whh2,
    const float* __restrict__ bih2, const float* __restrict__ bhh2,
    const float* __restrict__ Wih3, const float* __restrict__ Whh3,
    const float* __restrict__ bih3, const float* __restrict__ bhh3,
    float* __restrict__ out)
{
    __shared__ float ybuf[3 * 2 * 32];   // [layer][parity][h]
    __shared__ float xs[TT];             // staged x row

    const int tid  = threadIdx.x;
    const int wid  = __builtin_amdgcn_readfirstlane(tid >> 6);  // scalar layer id
    const int lane = tid & 63;
    const int h    = lane & 31;       // hidden unit
    const int kh   = lane >> 5;       // k-half
    const int k0   = kh * 16;
    const int bb   = (int)blockIdx.x; // batch index 0..511

    // ---- one-time staging ----
    if (tid < 192) ybuf[tid] = 0.0f;
    {
        const float4* xr4 = (const float4*)(x + bb * TT);
        for (int j = tid; j < TT / 4; j += 192) ((float4*)xs)[j] = xr4[j];
    }

    // ---- per-lane register weights (packed pairs), k-slice k0..k0+15 ----
    const float* WhhP = (wid == 0) ? Whh1 : (wid == 1) ? Whh2 : Whh3;
    const float* WihP = (wid == 0) ? Whh1 : (wid == 1) ? Wih2 : Wih3;  // dummy for wave0
    v2f whh[3][8], wih[3][8];
#pragma unroll
    for (int g = 0; g < 3; ++g) {
        load8(WhhP + (g * 32 + h) * 32 + k0, whh[g]);
        load8(WihP + (g * 32 + h) * 32 + k0, wih[g]);
    }
    // PIN: make weight values opaque so the compiler cannot re-load them
    // inside the step loop (R6: VGPR_Count=76 proved it was doing exactly that).
    if (wid != 0) {
#pragma unroll
        for (int g = 0; g < 3; ++g)
#pragma unroll
            for (int j = 0; j < 8; ++j) {
                asm volatile("" : "+v"(whh[g][j]));
                asm volatile("" : "+v"(wih[g][j]));
            }
    } else {
#pragma unroll
        for (int g = 0; g < 3; ++g)
#pragma unroll
            for (int j = 0; j < 8; ++j)
                asm volatile("" : "+v"(whh[g][j]));
    }

    const float* bihp = (wid == 0) ? bih1 : (wid == 1) ? bih2 : bih3;
    const float* bhhp = (wid == 0) ? bhh1 : (wid == 1) ? bhh2 : bhh3;
    const float brz_r = bihp[h]      + bhhp[h];
    const float brz_z = bihp[32 + h] + bhhp[32 + h];
    const float b_in  = bihp[64 + h];
    const float b_hn  = bhhp[64 + h];
    float wi_r = 0.f, wi_z = 0.f, wi_n = 0.f;
    if (wid == 0) { wi_r = Wih1[h]; wi_z = Wih1[32 + h]; wi_n = Wih1[64 + h]; }

    __syncthreads();   // full barrier once after staging

    float hprev = 0.0f;
    // pipelined: at iteration i, wave L computes timestep t = i - L
    for (int i = 0; i < TT + 2; ++i) {
        const int t = i - wid;           // scalar
        if (t >= 0 && t < TT) {          // scalar branch
            const int p = t & 1;

            v2f vi[8], vo[8];
            if (wid != 0) load8(ybuf + (wid - 1) * 64 + p * 32 + k0, vi);
            load8(ybuf + wid * 64 + (p ^ 1) * 32 + k0, vo);

            float di[3], dh[3];
            float xv = 0.f;
            if (wid == 0) xv = xs[t];
            if (wid != 0) dot3(wih, vi, di);   // runs while vo reads in flight
            dot3(whh, vo, dh);

            float r, z, nn;
            if (wid != 0) {
                float cr = dh[0] + di[0]; cr += __shfl_xor(cr, 32);
                float cz = dh[1] + di[1]; cz += __shfl_xor(cz, 32);
                float ci = di[2];         ci += __shfl_xor(ci, 32);
                float ch = dh[2];         ch += __shfl_xor(ch, 32);
                r  = fast_sigmoid(cr + brz_r);
                z  = fast_sigmoid(cz + brz_z);
                nn = fast_tanh(ci + b_in + r * (ch + b_hn));
            } else {
                float sr = dh[0]; sr += __shfl_xor(sr, 32);
                float sz = dh[1]; sz += __shfl_xor(sz, 32);
                float sn = dh[2]; sn += __shfl_xor(sn, 32);
                r  = fast_sigmoid(fmaf(xv, wi_r, sr + brz_r));
                z  = fast_sigmoid(fmaf(xv, wi_z, sz + brz_z));
                nn = fast_tanh(fmaf(xv, wi_n, b_in) + r * (sn + b_hn));
            }
            const float hn = fmaf(z, hprev - nn, nn);
            hprev = hn;

            if (kh == 0) {
                ybuf[wid * 64 + p * 32 + h] = hn;                 // publish h(t)
                if (wid == 2) out[t * 16384 + bb * 32 + h] = hn;  // [T,B,H] flat
            }
        }
        sync_lgkm();   // LDS-visibility barrier; global stores keep flying
    }
}

extern "C" void kernel_launch(void* const* d_in, const int* in_sizes, int n_in,
                              void* d_out, int out_size, void* d_ws, size_t ws_size,
                              hipStream_t stream) {
    const float* x    = (const float*)d_in[0];
    const float* Wih1 = (const float*)d_in[1];
    const float* Whh1 = (const float*)d_in[2];
    const float* bih1 = (const float*)d_in[3];
    const float* bhh1 = (const float*)d_in[4];
    const float* Wih2 = (const float*)d_in[5];
    const float* Whh2 = (const float*)d_in[6];
    const float* bih2 = (const float*)d_in[7];
    const float* bhh2 = (const float*)d_in[8];
    const float* Wih3 = (const float*)d_in[9];
    const float* Whh3 = (const float*)d_in[10];
    const float* bih3 = (const float*)d_in[11];
    const float* bhh3 = (const float*)d_in[12];

    gru3_fused<<<dim3(512), dim3(192), 0, stream>>>(
        x, Wih1, Whh1, bih1, bhh1,
        Wih2, Whh2, bih2, bhh2,
        Wih3, Whh3, bih3, bhh3,
        (float*)d_out);
}